// Round 6
// baseline (276.971 us; speedup 1.0000x reference)
//
#include <hip/hip_runtime.h>
#include <math.h>

#define C_IN   256
#define HW_    4096
#define KW_    769
#define NPIX_BN 32768.0f

typedef short bf16x8 __attribute__((ext_vector_type(8)));
typedef float f32x4  __attribute__((ext_vector_type(4)));
typedef unsigned short u16x8 __attribute__((ext_vector_type(8)));

__device__ inline unsigned short f2bf(float x){
    unsigned u = __float_as_uint(x);
    u += 0x7fffu + ((u >> 16) & 1u);      // RNE
    return (unsigned short)(u >> 16);
}
__device__ inline float bf2f(unsigned short h){
    return __uint_as_float(((unsigned)h) << 16);
}

// ---------------------------------------------------------------------------
// prep_w: w fp32 [256][769] -> wprep bf16 fragment-ordered, K=768 linear.
// chunk = (kn*4+kq)*256 + o holds k = kn*32+kq*8+j (j=0..7 contiguous bf16)
// ---------------------------------------------------------------------------
__global__ __launch_bounds__(256) void prep_w(
    const float* __restrict__ w, unsigned short* __restrict__ wp)
{
    int idx = blockIdx.x * 256 + threadIdx.x;     // 196608 total
    int j  = idx & 7;
    int o  = (idx >> 3) & 255;
    int t2 = idx >> 11;                           // kn*4 + kq, 0..95
    int c  = (t2 >> 2) * 32 + (t2 & 3) * 8 + j;   // global k 0..767
    wp[idx] = f2bf(w[(size_t)o * KW_ + c]);
}

// ---------------------------------------------------------------------------
// conv kernel: fp32 -> bf16 fragment staging of f_s, sfb, AND f_w=attn*f_s.
// grid 512 = b(8) x pgrp(64); 256 thr; wave g stages k-chunk kq=g.
// Plane layout per matrix: [(b*8+ks8)*4+kq][pixel 4096] x 16B.
// ---------------------------------------------------------------------------
__global__ __launch_bounds__(256) void conv_kernel(
    const float* __restrict__ f_s, const float* __restrict__ sfb,
    unsigned short* __restrict__ xf, unsigned short* __restrict__ xs,
    unsigned short* __restrict__ xw)
{
    __shared__ float red[4][64];
    __shared__ float attn_sm[64];
    int blk = blockIdx.x;
    int t = threadIdx.x, lane = t & 63, g = t >> 6;
    int b = blk >> 6;
    int p = (blk & 63) * 64 + lane;
    const float* fB = f_s + (size_t)b * C_IN * HW_ + p;
    const float* sB = sfb + (size_t)b * C_IN * HW_ + p;
    u16x8* XF = (u16x8*)xf;
    u16x8* XS = (u16x8*)xs;
    u16x8* XW = (u16x8*)xw;

    float ap = 0.f;
    u16x8 xfreg[8];
    float fv[8], sv[8], fv2[8], sv2[8];
    #pragma unroll
    for (int j = 0; j < 8; ++j) {
        fv[j] = fB[(size_t)(g * 8 + j) * HW_];
        sv[j] = sB[(size_t)(g * 8 + j) * HW_];
    }
    #pragma unroll
    for (int ks = 0; ks < 8; ++ks) {
        if (ks < 7) {
            #pragma unroll
            for (int j = 0; j < 8; ++j) {
                fv2[j] = fB[(size_t)((ks + 1) * 32 + g * 8 + j) * HW_];
                sv2[j] = sB[(size_t)((ks + 1) * 32 + g * 8 + j) * HW_];
            }
        }
        u16x8 pf, ps;
        #pragma unroll
        for (int j = 0; j < 8; ++j) {
            ap += fv[j] * sv[j];
            pf[j] = f2bf(fv[j]);
            ps[j] = f2bf(sv[j]);
        }
        int plane = (b * 8 + ks) * 4 + g;
        XF[(size_t)plane * HW_ + p] = pf;
        XS[(size_t)plane * HW_ + p] = ps;
        xfreg[ks] = pf;
        #pragma unroll
        for (int j = 0; j < 8; ++j) { fv[j] = fv2[j]; sv[j] = sv2[j]; }
    }
    red[g][lane] = ap;
    __syncthreads();
    if (t < 64) {
        float a = red[0][t] + red[1][t] + red[2][t] + red[3][t];
        attn_sm[t] = 1.f / (1.f + __expf(-a));
    }
    __syncthreads();
    float at = attn_sm[lane];
    #pragma unroll
    for (int ks = 0; ks < 8; ++ks) {
        u16x8 pw;
        #pragma unroll
        for (int j = 0; j < 8; ++j)
            pw[j] = f2bf(bf2f(xfreg[ks][j]) * at);
        XW[(size_t)((b * 8 + ks) * 4 + g) * HW_ + p] = pw;
    }
}

// ---------------------------------------------------------------------------
// dist kernel: packed-uint fg list, integer d2, grid (8,32) x 512 thr.
// ---------------------------------------------------------------------------
__global__ __launch_bounds__(512) void dist_kernel(
    const float* __restrict__ mask, float* __restrict__ dist_raw,
    unsigned* __restrict__ dmax)
{
    __shared__ unsigned fg[4096];
    __shared__ int cnt;
    __shared__ float wmax[8];
    int b = blockIdx.x, tile = blockIdx.y;
    int t = threadIdx.x, lane = t & 63;
    if (t == 0) cnt = 0;
    __syncthreads();
    const float* mb = mask + (size_t)b * 65536;
    #pragma unroll
    for (int r = 0; r < 8; ++r) {
        int pp = r * 512 + t;
        int i = pp >> 6, j = pp & 63;
        bool pred = mb[i * 1024 + j * 4] > 0.5f;
        unsigned long long bal = __ballot(pred);
        int base = 0;
        if (lane == 0) base = atomicAdd(&cnt, __popcll(bal));
        base = __shfl(base, 0, 64);
        if (pred)
            fg[base + __popcll(bal & ((1ull << lane) - 1ull))] =
                (unsigned)((i << 8) | j);
    }
    __syncthreads();
    int nfg = cnt;
    int pix = tile * 128 + (t >> 2);
    int q = t & 3;
    int py = pix >> 6, px = pix & 63;
    int md = 0x7fffffff;
    #pragma unroll 4
    for (int it = q; it < nfg; it += 4) {
        unsigned e = fg[it];
        int dy = py - (int)(e >> 8);
        int dx = px - (int)(e & 255u);
        int d2 = dy * dy + dx * dx;
        md = min(md, d2);
    }
    md = min(md, __shfl_xor(md, 1, 64));
    md = min(md, __shfl_xor(md, 2, 64));
    float d = (nfg == 0) ? 1.0f : sqrtf((float)md);
    if (q == 0) dist_raw[b * HW_ + pix] = d;
    float mm = d;
    #pragma unroll
    for (int off = 1; off < 64; off <<= 1)
        mm = fmaxf(mm, __shfl_xor(mm, off, 64));
    if (lane == 0) wmax[t >> 6] = mm;
    __syncthreads();
    if (t == 0) {
        float M = wmax[0];
        #pragma unroll
        for (int i = 1; i < 8; ++i) M = fmaxf(M, wmax[i]);
        atomicMax(dmax + b, __float_as_uint(M));
    }
}

// ---------------------------------------------------------------------------
// Single MFMA GEMM: M=256, N=32768, K=768. Barrier/LDS-free.
// 128o x 64n block, 4 waves (2wo x 2wn), wave = 64o x 32n, acc 32 VGPR.
// Grid 1024 -> 4 blocks/CU -> 16 waves/CU; __launch_bounds__(256,4) caps
// VGPR at 128 so 4 waves/SIMD materialize.
// Rotating register pipeline: A depth-2 (L2), X depth-3 (L3/HBM) via 6-step
// unrolled macro schedule (indices all compile-time; no scratch).
// ---------------------------------------------------------------------------
__global__ __launch_bounds__(256, 4) void gemm_kernel(
    const unsigned short* __restrict__ xf, const unsigned short* __restrict__ xs,
    const unsigned short* __restrict__ xw, const unsigned short* __restrict__ wprep,
    const float* __restrict__ w,
    const float* __restrict__ dist_raw, const unsigned* __restrict__ dmax,
    unsigned short* __restrict__ ybf,
    float* __restrict__ gsum, float* __restrict__ gsumsq)
{
    int bx = blockIdx.x;
    int ot = bx & 1, nt = bx >> 1;              // 2 o-tiles x 512 n-tiles
    int oBase = ot * 128, nBase = nt * 64;
    int b = nBase >> 12, pBase = nBase & 4095;
    int t = threadIdx.x, lane = t & 63, g = t >> 6;
    int wo = g >> 1, wn = g & 1;
    int l15 = lane & 15, kq = lane >> 4;
    int oW = oBase + wo * 64;
    int pix0 = pBase + wn * 32 + l15;

    const bf16x8* WP  = (const bf16x8*)wprep;
    const bf16x8* XFp = (const bf16x8*)xf;
    const bf16x8* XSp = (const bf16x8*)xs;
    const bf16x8* XWp = (const bf16x8*)xw;

    f32x4 acc[4][2];
    #pragma unroll
    for (int fo = 0; fo < 4; ++fo)
        #pragma unroll
        for (int fn = 0; fn < 2; ++fn)
            acc[fo][fn] = (f32x4){0.f, 0.f, 0.f, 0.f};

    bf16x8 aP0[4], aP1[4], xP0[2], xP1[2], xP2[2];

#define LOADA(kn, dst) { \
    const bf16x8* _wp = WP + ((kn) * 4 + kq) * 256 + oW + l15; \
    dst[0] = _wp[0]; dst[1] = _wp[16]; dst[2] = _wp[32]; dst[3] = _wp[48]; }

#define LOADX(kn, dst) { \
    const bf16x8* _xp = ((kn) < 8 ? XFp : ((kn) < 16 ? XSp : XWp)) \
        + (size_t)((b * 8 + ((kn) & 7)) * 4 + kq) * HW_ + pix0; \
    dst[0] = _xp[0]; dst[1] = _xp[16]; }

#define MFMA8(A, X) { \
    _Pragma("unroll") \
    for (int fo = 0; fo < 4; ++fo) { \
        acc[fo][0] = __builtin_amdgcn_mfma_f32_16x16x32_bf16(A[fo], X[0], acc[fo][0], 0, 0, 0); \
        acc[fo][1] = __builtin_amdgcn_mfma_f32_16x16x32_bf16(A[fo], X[1], acc[fo][1], 0, 0, 0); } }

#define STEP(kn, A, X) { \
    MFMA8(A, X); \
    if ((kn) + 2 < 24) LOADA((kn) + 2, A); \
    if ((kn) + 3 < 24) LOADX((kn) + 3, X); }

    LOADX(0, xP0); LOADX(1, xP1); LOADX(2, xP2);
    LOADA(0, aP0); LOADA(1, aP1);

    #pragma unroll
    for (int kb = 0; kb < 24; kb += 6) {
        STEP(kb + 0, aP0, xP0);
        STEP(kb + 1, aP1, xP1);
        STEP(kb + 2, aP0, xP2);
        STEP(kb + 3, aP1, xP0);
        STEP(kb + 4, aP0, xP1);
        STEP(kb + 5, aP1, xP2);
    }
#undef STEP
#undef MFMA8
#undef LOADX
#undef LOADA

    // ---- epilogue ----
    float dinv = 1.0f / (__uint_as_float(dmax[b]) + 1e-6f);
    const float* dR = dist_raw + b * HW_ + pBase + wn * 32;
    float dn[2];
    #pragma unroll
    for (int fn = 0; fn < 2; ++fn)
        dn[fn] = dR[fn * 16 + l15] * dinv;

    float s_acc[4][4], ss_acc[4][4];
    #pragma unroll
    for (int fo = 0; fo < 4; ++fo) {
        #pragma unroll
        for (int r = 0; r < 4; ++r) {
            int o = oW + fo * 16 + kq * 4 + r;
            float wd = w[(size_t)o * KW_ + 768];
            float s = 0.f, ss = 0.f;
            #pragma unroll
            for (int fn = 0; fn < 2; ++fn) {
                float v = acc[fo][fn][r] + wd * dn[fn];
                ybf[((size_t)(b * C_IN + o)) * HW_ + pBase + wn * 32 + fn * 16 + l15] = f2bf(v);
                s += v; ss += v * v;
            }
            s_acc[fo][r] = s; ss_acc[fo][r] = ss;
        }
    }
    #pragma unroll
    for (int m = 8; m; m >>= 1) {
        #pragma unroll
        for (int fo = 0; fo < 4; ++fo)
            #pragma unroll
            for (int r = 0; r < 4; ++r) {
                s_acc[fo][r]  += __shfl_xor(s_acc[fo][r],  m, 64);
                ss_acc[fo][r] += __shfl_xor(ss_acc[fo][r], m, 64);
            }
    }
    if (l15 == 0) {
        #pragma unroll
        for (int fo = 0; fo < 4; ++fo)
            #pragma unroll
            for (int r = 0; r < 4; ++r) {
                int o = oW + fo * 16 + kq * 4 + r;
                atomicAdd(&gsum[o],   s_acc[fo][r]);
                atomicAdd(&gsumsq[o], ss_acc[fo][r]);
            }
    }
}

// ---------------------------------------------------------------------------
// BN finalize + relu: read bf16 y, write fp32 out.
// ---------------------------------------------------------------------------
__global__ __launch_bounds__(256) void bn_kernel(
    const float* __restrict__ gsum, const float* __restrict__ gsumsq,
    const float* __restrict__ gamma, const float* __restrict__ beta,
    const unsigned short* __restrict__ ybf, float* __restrict__ out)
{
    int bo = blockIdx.x;
    int o = bo & 255;
    float mean = gsum[o] * (1.0f / NPIX_BN);
    float var  = gsumsq[o] * (1.0f / NPIX_BN) - mean * mean;
    float sc = gamma[o] * rsqrtf(var + 1e-5f);
    float sh = beta[o] - mean * sc;
    const u16x8* yp = (const u16x8*)(ybf + (size_t)bo * HW_);
    float4* op = (float4*)(out + (size_t)bo * HW_);
    int t = threadIdx.x;
    #pragma unroll
    for (int r = 0; r < 2; ++r) {
        u16x8 v = yp[r * 256 + t];
        float4 lo, hi;
        lo.x = fmaxf(bf2f(v[0]) * sc + sh, 0.f);
        lo.y = fmaxf(bf2f(v[1]) * sc + sh, 0.f);
        lo.z = fmaxf(bf2f(v[2]) * sc + sh, 0.f);
        lo.w = fmaxf(bf2f(v[3]) * sc + sh, 0.f);
        hi.x = fmaxf(bf2f(v[4]) * sc + sh, 0.f);
        hi.y = fmaxf(bf2f(v[5]) * sc + sh, 0.f);
        hi.z = fmaxf(bf2f(v[6]) * sc + sh, 0.f);
        hi.w = fmaxf(bf2f(v[7]) * sc + sh, 0.f);
        op[(r * 256 + t) * 2]     = lo;
        op[(r * 256 + t) * 2 + 1] = hi;
    }
}

// ---------------------------------------------------------------------------
// ws layout (float units):
//   [0,     32768)   dist_raw
//   [32768, 32776)   dmax (uint)
//   [32784, 33040)   gsum
//   [33040, 33296)   gsumsq
//   [33296, 131600)  wprep (196608 ushort)
//   [131600, ...)    staging:
//     P1 (ws >= ~68MB): XF | XS | XW | ybf (4 x 4194304 floats)
//     P2 (else):        XF,XS in d_out (consumed by gemm before bn rewrites
//                       d_out); XW | ybf in ws.
// ---------------------------------------------------------------------------
extern "C" void kernel_launch(void* const* d_in, const int* in_sizes, int n_in,
                              void* d_out, int out_size, void* d_ws, size_t ws_size,
                              hipStream_t stream)
{
    const float* f_s   = (const float*)d_in[0];
    const float* sfb   = (const float*)d_in[1];
    const float* mask  = (const float*)d_in[2];
    const float* w     = (const float*)d_in[3];
    const float* gamma = (const float*)d_in[4];
    const float* beta  = (const float*)d_in[5];
    float* out = (float*)d_out;
    float* ws  = (float*)d_ws;

    float*          dist_raw = ws;
    unsigned*       dmax     = (unsigned*)(ws + 32768);
    float*          gsum     = ws + 32784;
    float*          gsumsq   = ws + 33040;
    unsigned short* wprep    = (unsigned short*)(ws + 33296);

    const size_t P1_need = ((size_t)131600 + 4 * 4194304) * 4;  // ~67.6 MB
    unsigned short *xf, *xs, *xw, *ybf;
    if (ws_size >= P1_need) {
        xf  = (unsigned short*)(ws + 131600);
        xs  = (unsigned short*)(ws + 131600 + 1 * (size_t)4194304);
        xw  = (unsigned short*)(ws + 131600 + 2 * (size_t)4194304);
        ybf = (unsigned short*)(ws + 131600 + 3 * (size_t)4194304);
    } else {
        xf  = (unsigned short*)d_out;
        xs  = ((unsigned short*)d_out) + 8388608;
        xw  = (unsigned short*)(ws + 131600);
        ybf = (unsigned short*)(ws + 131600 + (size_t)4194304);
    }

    hipMemsetAsync(ws + 32768, 0, (33296 - 32768) * 4, stream);

    prep_w<<<768, 256, 0, stream>>>(w, wprep);
    conv_kernel<<<512, 256, 0, stream>>>(f_s, sfb, xf, xs, xw);
    dist_kernel<<<dim3(8, 32), 512, 0, stream>>>(mask, dist_raw, dmax);
    gemm_kernel<<<1024, 256, 0, stream>>>(xf, xs, xw, wprep, w, dist_raw,
                                          dmax, ybf, gsum, gsumsq);
    bn_kernel<<<2048, 256, 0, stream>>>(gsum, gsumsq, gamma, beta, ybf, out);
}

// Round 7
// 229.175 us; speedup vs baseline: 1.2086x; 1.2086x over previous
//
#include <hip/hip_runtime.h>
#include <math.h>

#define C_IN   256
#define HW_    4096
#define KW_    769
#define NPIX_BN 32768.0f

typedef short bf16x8 __attribute__((ext_vector_type(8)));
typedef float f32x4  __attribute__((ext_vector_type(4)));
typedef unsigned short u16x8 __attribute__((ext_vector_type(8)));

__device__ inline unsigned short f2bf(float x){
    unsigned u = __float_as_uint(x);
    u += 0x7fffu + ((u >> 16) & 1u);      // RNE
    return (unsigned short)(u >> 16);
}
__device__ inline float bf2f(unsigned short h){
    return __uint_as_float(((unsigned)h) << 16);
}

// async global->LDS, 16B per lane; LDS dest = wave-uniform base + lane*16
#define GLOAD16(gp, lp) \
    __builtin_amdgcn_global_load_lds( \
        (const __attribute__((address_space(1))) void*)(gp), \
        (__attribute__((address_space(3))) void*)(lp), 16, 0, 0)

// ---------------------------------------------------------------------------
// prep_w: w fp32 [256][769] -> wprep bf16 fragment-ordered, K=768 linear.
// chunk = (kn*4+kq)*256 + o holds k = kn*32+kq*8+j (j=0..7 contiguous bf16)
// ---------------------------------------------------------------------------
__global__ __launch_bounds__(256) void prep_w(
    const float* __restrict__ w, unsigned short* __restrict__ wp)
{
    int idx = blockIdx.x * 256 + threadIdx.x;     // 196608 total
    int j  = idx & 7;
    int o  = (idx >> 3) & 255;
    int t2 = idx >> 11;                           // kn*4 + kq, 0..95
    int c  = (t2 >> 2) * 32 + (t2 & 3) * 8 + j;   // global k 0..767
    wp[idx] = f2bf(w[(size_t)o * KW_ + c]);
}

// ---------------------------------------------------------------------------
// conv kernel: fp32 -> bf16 fragment staging of f_s, sfb, AND f_w=attn*f_s.
// grid 512 = b(8) x pgrp(64); 256 thr; wave g stages k-chunk kq=g.
// Plane layout per matrix: [(b*8+ks8)*4+kq][pixel 4096] x 16B.
// ---------------------------------------------------------------------------
__global__ __launch_bounds__(256) void conv_kernel(
    const float* __restrict__ f_s, const float* __restrict__ sfb,
    unsigned short* __restrict__ xf, unsigned short* __restrict__ xs,
    unsigned short* __restrict__ xw)
{
    __shared__ float red[4][64];
    __shared__ float attn_sm[64];
    int blk = blockIdx.x;
    int t = threadIdx.x, lane = t & 63, g = t >> 6;
    int b = blk >> 6;
    int p = (blk & 63) * 64 + lane;
    const float* fB = f_s + (size_t)b * C_IN * HW_ + p;
    const float* sB = sfb + (size_t)b * C_IN * HW_ + p;
    u16x8* XF = (u16x8*)xf;
    u16x8* XS = (u16x8*)xs;
    u16x8* XW = (u16x8*)xw;

    float ap = 0.f;
    u16x8 xfreg[8];
    float fv[8], sv[8], fv2[8], sv2[8];
    #pragma unroll
    for (int j = 0; j < 8; ++j) {
        fv[j] = fB[(size_t)(g * 8 + j) * HW_];
        sv[j] = sB[(size_t)(g * 8 + j) * HW_];
    }
    #pragma unroll
    for (int ks = 0; ks < 8; ++ks) {
        if (ks < 7) {
            #pragma unroll
            for (int j = 0; j < 8; ++j) {
                fv2[j] = fB[(size_t)((ks + 1) * 32 + g * 8 + j) * HW_];
                sv2[j] = sB[(size_t)((ks + 1) * 32 + g * 8 + j) * HW_];
            }
        }
        u16x8 pf, ps;
        #pragma unroll
        for (int j = 0; j < 8; ++j) {
            ap += fv[j] * sv[j];
            pf[j] = f2bf(fv[j]);
            ps[j] = f2bf(sv[j]);
        }
        int plane = (b * 8 + ks) * 4 + g;
        XF[(size_t)plane * HW_ + p] = pf;
        XS[(size_t)plane * HW_ + p] = ps;
        xfreg[ks] = pf;
        #pragma unroll
        for (int j = 0; j < 8; ++j) { fv[j] = fv2[j]; sv[j] = sv2[j]; }
    }
    red[g][lane] = ap;
    __syncthreads();
    if (t < 64) {
        float a = red[0][t] + red[1][t] + red[2][t] + red[3][t];
        attn_sm[t] = 1.f / (1.f + __expf(-a));
    }
    __syncthreads();
    float at = attn_sm[lane];
    #pragma unroll
    for (int ks = 0; ks < 8; ++ks) {
        u16x8 pw;
        #pragma unroll
        for (int j = 0; j < 8; ++j)
            pw[j] = f2bf(bf2f(xfreg[ks][j]) * at);
        XW[(size_t)((b * 8 + ks) * 4 + g) * HW_ + p] = pw;
    }
}

// ---------------------------------------------------------------------------
// dist kernel: packed-uint fg list, integer d2, grid (8,32) x 512 thr.
// ---------------------------------------------------------------------------
__global__ __launch_bounds__(512) void dist_kernel(
    const float* __restrict__ mask, float* __restrict__ dist_raw,
    unsigned* __restrict__ dmax)
{
    __shared__ unsigned fg[4096];
    __shared__ int cnt;
    __shared__ float wmax[8];
    int b = blockIdx.x, tile = blockIdx.y;
    int t = threadIdx.x, lane = t & 63;
    if (t == 0) cnt = 0;
    __syncthreads();
    const float* mb = mask + (size_t)b * 65536;
    #pragma unroll
    for (int r = 0; r < 8; ++r) {
        int pp = r * 512 + t;
        int i = pp >> 6, j = pp & 63;
        bool pred = mb[i * 1024 + j * 4] > 0.5f;
        unsigned long long bal = __ballot(pred);
        int base = 0;
        if (lane == 0) base = atomicAdd(&cnt, __popcll(bal));
        base = __shfl(base, 0, 64);
        if (pred)
            fg[base + __popcll(bal & ((1ull << lane) - 1ull))] =
                (unsigned)((i << 8) | j);
    }
    __syncthreads();
    int nfg = cnt;
    int pix = tile * 128 + (t >> 2);
    int q = t & 3;
    int py = pix >> 6, px = pix & 63;
    int md = 0x7fffffff;
    #pragma unroll 4
    for (int it = q; it < nfg; it += 4) {
        unsigned e = fg[it];
        int dy = py - (int)(e >> 8);
        int dx = px - (int)(e & 255u);
        int d2 = dy * dy + dx * dx;
        md = min(md, d2);
    }
    md = min(md, __shfl_xor(md, 1, 64));
    md = min(md, __shfl_xor(md, 2, 64));
    float d = (nfg == 0) ? 1.0f : sqrtf((float)md);
    if (q == 0) dist_raw[b * HW_ + pix] = d;
    float mm = d;
    #pragma unroll
    for (int off = 1; off < 64; off <<= 1)
        mm = fmaxf(mm, __shfl_xor(mm, off, 64));
    if (lane == 0) wmax[t >> 6] = mm;
    __syncthreads();
    if (t == 0) {
        float M = wmax[0];
        #pragma unroll
        for (int i = 1; i < 8; ++i) M = fmaxf(M, wmax[i]);
        atomicMax(dmax + b, __float_as_uint(M));
    }
}

// ---------------------------------------------------------------------------
// MFMA GEMM, m97 structure: M=256, N=32768, K=768.
// 128o x 128n tile, 4 waves (64o x 64n), acc[4][4] f32x4.
// Per K-step(32): 4x global_load_lds_dwordx4 (A:8KB + X:8KB), barrier,
// 8x ds_read_b128 + 16 MFMA, barrier. Single-buffered LDS (16KB).
// LDS layout [kq(4)][row(128)] of 16B chunks, linear in staging-lane order.
// Epilogue: + wd*dist, bf16 y store, BN partial stats.
// ---------------------------------------------------------------------------
__global__ __launch_bounds__(256) void gemm_kernel(
    const unsigned short* __restrict__ xf, const unsigned short* __restrict__ xs,
    const unsigned short* __restrict__ xw, const unsigned short* __restrict__ wprep,
    const float* __restrict__ w,
    const float* __restrict__ dist_raw, const unsigned* __restrict__ dmax,
    unsigned short* __restrict__ ybf,
    float* __restrict__ gsum, float* __restrict__ gsumsq)
{
    __shared__ u16x8 LA[512];   // [kq(4)][o(128)] 16B chunks = 8 KB
    __shared__ u16x8 LX[512];   // [kq(4)][n(128)] 16B chunks = 8 KB

    int bx = blockIdx.x;
    int ot = bx & 1, nt = bx >> 1;              // 2 o-tiles x 256 n-tiles
    int oBase = ot * 128, nBase = nt * 128;
    int b = nBase >> 12, pBase = nBase & 4095;  // 32 n-tiles/sample, no crossing
    int t = threadIdx.x, lane = t & 63, g = t >> 6;
    int wo = g >> 1, wn = g & 1;
    int l15 = lane & 15, kq = lane >> 4;
    int oW = oBase + wo * 64;

    const u16x8* WPc = (const u16x8*)wprep;
    const u16x8* XFc = (const u16x8*)xf;
    const u16x8* XSc = (const u16x8*)xs;
    const u16x8* XWc = (const u16x8*)xw;
    const bf16x8* LAr = (const bf16x8*)LA;
    const bf16x8* LXr = (const bf16x8*)LX;

    // staging slot decomposition: slot ci -> [kqs = ci>>7][rl = ci&127]
    int kq0 = t >> 7;          // issue 0: ci = t
    int kq1 = 2 + (t >> 7);    // issue 1: ci = 256 + t
    int rl  = t & 127;
    // wave-uniform LDS bases (slots g*64 and 256+g*64)
    u16x8* dstA0 = &LA[g * 64];
    u16x8* dstA1 = &LA[256 + g * 64];
    u16x8* dstX0 = &LX[g * 64];
    u16x8* dstX1 = &LX[256 + g * 64];

    f32x4 acc[4][4];
    #pragma unroll
    for (int fo = 0; fo < 4; ++fo)
        #pragma unroll
        for (int fn = 0; fn < 4; ++fn)
            acc[fo][fn] = (f32x4){0.f, 0.f, 0.f, 0.f};

    #pragma unroll
    for (int kn = 0; kn < 24; ++kn) {
        int k8 = kn & 7;
        const u16x8* Xsel = (kn < 8) ? XFc : ((kn < 16) ? XSc : XWc);
        // ---- stage A (8KB) + X (8KB) via async global->LDS ----
        GLOAD16(WPc + (kn * 4 + kq0) * 256 + oBase + rl, dstA0);
        GLOAD16(WPc + (kn * 4 + kq1) * 256 + oBase + rl, dstA1);
        GLOAD16(Xsel + (size_t)((b * 8 + k8) * 4 + kq0) * HW_ + pBase + rl, dstX0);
        GLOAD16(Xsel + (size_t)((b * 8 + k8) * 4 + kq1) * HW_ + pBase + rl, dstX1);
        __syncthreads();   // compiler drains vmcnt(0) before barrier
        // ---- fragments + MFMA ----
        bf16x8 af[4], xr[4];
        #pragma unroll
        for (int fo = 0; fo < 4; ++fo)
            af[fo] = LAr[kq * 128 + wo * 64 + fo * 16 + l15];
        #pragma unroll
        for (int fn = 0; fn < 4; ++fn)
            xr[fn] = LXr[kq * 128 + wn * 64 + fn * 16 + l15];
        #pragma unroll
        for (int fo = 0; fo < 4; ++fo)
            #pragma unroll
            for (int fn = 0; fn < 4; ++fn)
                acc[fo][fn] = __builtin_amdgcn_mfma_f32_16x16x32_bf16(
                    af[fo], xr[fn], acc[fo][fn], 0, 0, 0);
        __syncthreads();   // all reads done before next overwrite
    }

    // ---- epilogue ----
    float dinv = 1.0f / (__uint_as_float(dmax[b]) + 1e-6f);
    const float* dR = dist_raw + b * HW_ + pBase + wn * 64;
    float dn[4];
    #pragma unroll
    for (int fn = 0; fn < 4; ++fn)
        dn[fn] = dR[fn * 16 + l15] * dinv;

    float s_acc[4][4], ss_acc[4][4];
    #pragma unroll
    for (int fo = 0; fo < 4; ++fo) {
        #pragma unroll
        for (int r = 0; r < 4; ++r) {
            int o = oW + fo * 16 + kq * 4 + r;
            float wd = w[(size_t)o * KW_ + 768];
            float s = 0.f, ss = 0.f;
            #pragma unroll
            for (int fn = 0; fn < 4; ++fn) {
                float v = acc[fo][fn][r] + wd * dn[fn];
                ybf[((size_t)(b * C_IN + o)) * HW_ + pBase + wn * 64 + fn * 16 + l15] = f2bf(v);
                s += v; ss += v * v;
            }
            s_acc[fo][r] = s; ss_acc[fo][r] = ss;
        }
    }
    #pragma unroll
    for (int m = 8; m; m >>= 1) {
        #pragma unroll
        for (int fo = 0; fo < 4; ++fo)
            #pragma unroll
            for (int r = 0; r < 4; ++r) {
                s_acc[fo][r]  += __shfl_xor(s_acc[fo][r],  m, 64);
                ss_acc[fo][r] += __shfl_xor(ss_acc[fo][r], m, 64);
            }
    }
    if (l15 == 0) {
        #pragma unroll
        for (int fo = 0; fo < 4; ++fo)
            #pragma unroll
            for (int r = 0; r < 4; ++r) {
                int o = oW + fo * 16 + kq * 4 + r;
                atomicAdd(&gsum[o],   s_acc[fo][r]);
                atomicAdd(&gsumsq[o], ss_acc[fo][r]);
            }
    }
}

// ---------------------------------------------------------------------------
// BN finalize + relu: read bf16 y, write fp32 out.
// ---------------------------------------------------------------------------
__global__ __launch_bounds__(256) void bn_kernel(
    const float* __restrict__ gsum, const float* __restrict__ gsumsq,
    const float* __restrict__ gamma, const float* __restrict__ beta,
    const unsigned short* __restrict__ ybf, float* __restrict__ out)
{
    int bo = blockIdx.x;
    int o = bo & 255;
    float mean = gsum[o] * (1.0f / NPIX_BN);
    float var  = gsumsq[o] * (1.0f / NPIX_BN) - mean * mean;
    float sc = gamma[o] * rsqrtf(var + 1e-5f);
    float sh = beta[o] - mean * sc;
    const u16x8* yp = (const u16x8*)(ybf + (size_t)bo * HW_);
    float4* op = (float4*)(out + (size_t)bo * HW_);
    int t = threadIdx.x;
    #pragma unroll
    for (int r = 0; r < 2; ++r) {
        u16x8 v = yp[r * 256 + t];
        float4 lo, hi;
        lo.x = fmaxf(bf2f(v[0]) * sc + sh, 0.f);
        lo.y = fmaxf(bf2f(v[1]) * sc + sh, 0.f);
        lo.z = fmaxf(bf2f(v[2]) * sc + sh, 0.f);
        lo.w = fmaxf(bf2f(v[3]) * sc + sh, 0.f);
        hi.x = fmaxf(bf2f(v[4]) * sc + sh, 0.f);
        hi.y = fmaxf(bf2f(v[5]) * sc + sh, 0.f);
        hi.z = fmaxf(bf2f(v[6]) * sc + sh, 0.f);
        hi.w = fmaxf(bf2f(v[7]) * sc + sh, 0.f);
        op[(r * 256 + t) * 2]     = lo;
        op[(r * 256 + t) * 2 + 1] = hi;
    }
}

// ---------------------------------------------------------------------------
// ws layout (float units):
//   [0,     32768)   dist_raw
//   [32768, 32776)   dmax (uint)
//   [32784, 33040)   gsum
//   [33040, 33296)   gsumsq
//   [33296, 131600)  wprep (196608 ushort)
//   [131600, ...)    staging:
//     P1 (ws >= ~68MB): XF | XS | XW | ybf (4 x 4194304 floats)
//     P2 (else):        XF,XS in d_out (consumed by gemm before bn rewrites
//                       d_out); XW | ybf in ws.
// ---------------------------------------------------------------------------
extern "C" void kernel_launch(void* const* d_in, const int* in_sizes, int n_in,
                              void* d_out, int out_size, void* d_ws, size_t ws_size,
                              hipStream_t stream)
{
    const float* f_s   = (const float*)d_in[0];
    const float* sfb   = (const float*)d_in[1];
    const float* mask  = (const float*)d_in[2];
    const float* w     = (const float*)d_in[3];
    const float* gamma = (const float*)d_in[4];
    const float* beta  = (const float*)d_in[5];
    float* out = (float*)d_out;
    float* ws  = (float*)d_ws;

    float*          dist_raw = ws;
    unsigned*       dmax     = (unsigned*)(ws + 32768);
    float*          gsum     = ws + 32784;
    float*          gsumsq   = ws + 33040;
    unsigned short* wprep    = (unsigned short*)(ws + 33296);

    const size_t P1_need = ((size_t)131600 + 4 * 4194304) * 4;  // ~67.6 MB
    unsigned short *xf, *xs, *xw, *ybf;
    if (ws_size >= P1_need) {
        xf  = (unsigned short*)(ws + 131600);
        xs  = (unsigned short*)(ws + 131600 + 1 * (size_t)4194304);
        xw  = (unsigned short*)(ws + 131600 + 2 * (size_t)4194304);
        ybf = (unsigned short*)(ws + 131600 + 3 * (size_t)4194304);
    } else {
        xf  = (unsigned short*)d_out;
        xs  = ((unsigned short*)d_out) + 8388608;
        xw  = (unsigned short*)(ws + 131600);
        ybf = (unsigned short*)(ws + 131600 + (size_t)4194304);
    }

    hipMemsetAsync(ws + 32768, 0, (33296 - 32768) * 4, stream);

    prep_w<<<768, 256, 0, stream>>>(w, wprep);
    conv_kernel<<<512, 256, 0, stream>>>(f_s, sfb, xf, xs, xw);
    dist_kernel<<<dim3(8, 32), 512, 0, stream>>>(mask, dist_raw, dmax);
    gemm_kernel<<<512, 256, 0, stream>>>(xf, xs, xw, wprep, w, dist_raw,
                                         dmax, ybf, gsum, gsumsq);
    bn_kernel<<<2048, 256, 0, stream>>>(gsum, gsumsq, gamma, beta, ybf, out);
}

// Round 8
// 227.828 us; speedup vs baseline: 1.2157x; 1.0059x over previous
//
#include <hip/hip_runtime.h>
#include <math.h>

#define C_IN   256
#define HW_    4096
#define KW_    769
#define NPIX_BN 32768.0f

typedef short bf16x8 __attribute__((ext_vector_type(8)));
typedef float f32x4  __attribute__((ext_vector_type(4)));
typedef unsigned short u16x8 __attribute__((ext_vector_type(8)));

__device__ inline unsigned short f2bf(float x){
    unsigned u = __float_as_uint(x);
    u += 0x7fffu + ((u >> 16) & 1u);      // RNE
    return (unsigned short)(u >> 16);
}
__device__ inline float bf2f(unsigned short h){
    return __uint_as_float(((unsigned)h) << 16);
}

// async global->LDS, 16B per lane; LDS dest = wave-uniform base + lane*16
#define GLOAD16(gp, lp) \
    __builtin_amdgcn_global_load_lds( \
        (const __attribute__((address_space(1))) void*)(gp), \
        (__attribute__((address_space(3))) void*)(lp), 16, 0, 0)

// ---------------------------------------------------------------------------
// prep_w: w fp32 [256][769] -> wprep bf16 fragment-ordered, K=768 linear.
// chunk = (kn*4+kq)*256 + o holds k = kn*32+kq*8+j (j=0..7 contiguous bf16)
// ---------------------------------------------------------------------------
__global__ __launch_bounds__(256) void prep_w(
    const float* __restrict__ w, unsigned short* __restrict__ wp)
{
    int idx = blockIdx.x * 256 + threadIdx.x;     // 196608 total
    int j  = idx & 7;
    int o  = (idx >> 3) & 255;
    int t2 = idx >> 11;                           // kn*4 + kq, 0..95
    int c  = (t2 >> 2) * 32 + (t2 & 3) * 8 + j;   // global k 0..767
    wp[idx] = f2bf(w[(size_t)o * KW_ + c]);
}

// ---------------------------------------------------------------------------
// conv kernel: fp32 -> bf16 fragment staging of f_s, sfb, AND f_w=attn*f_s.
// grid 512 = b(8) x pgrp(64); 512 thr (8 waves): wave g covers plane
// kq=g&3, ks = (g>>2)+2i (i=0..3) -> 4 serial iters/wave (was 8).
// Plane layout per matrix: [(b*8+ks)*4+kq][pixel 4096] x 16B.
// ---------------------------------------------------------------------------
__global__ __launch_bounds__(512) void conv_kernel(
    const float* __restrict__ f_s, const float* __restrict__ sfb,
    unsigned short* __restrict__ xf, unsigned short* __restrict__ xs,
    unsigned short* __restrict__ xw)
{
    __shared__ float red[8][64];
    __shared__ float attn_sm[64];
    int blk = blockIdx.x;
    int t = threadIdx.x, lane = t & 63, g = t >> 6;   // g = 0..7
    int b = blk >> 6;
    int p = (blk & 63) * 64 + lane;
    int kq  = g & 3;
    int ks0 = g >> 2;                                  // ks = ks0 + 2*i
    const float* fB = f_s + (size_t)b * C_IN * HW_ + p;
    const float* sB = sfb + (size_t)b * C_IN * HW_ + p;
    u16x8* XF = (u16x8*)xf;
    u16x8* XS = (u16x8*)xs;
    u16x8* XW = (u16x8*)xw;

    float ap = 0.f;
    u16x8 xfreg[4];
    float fv[8], sv[8], fv2[8], sv2[8];
    #pragma unroll
    for (int j = 0; j < 8; ++j) {
        int c = ks0 * 32 + kq * 8 + j;
        fv[j] = fB[(size_t)c * HW_];
        sv[j] = sB[(size_t)c * HW_];
    }
    #pragma unroll
    for (int i = 0; i < 4; ++i) {
        int ks = ks0 + 2 * i;
        if (i < 3) {
            #pragma unroll
            for (int j = 0; j < 8; ++j) {
                int c = (ks + 2) * 32 + kq * 8 + j;
                fv2[j] = fB[(size_t)c * HW_];
                sv2[j] = sB[(size_t)c * HW_];
            }
        }
        u16x8 pf, ps;
        #pragma unroll
        for (int j = 0; j < 8; ++j) {
            ap += fv[j] * sv[j];
            pf[j] = f2bf(fv[j]);
            ps[j] = f2bf(sv[j]);
        }
        int plane = (b * 8 + ks) * 4 + kq;
        XF[(size_t)plane * HW_ + p] = pf;
        XS[(size_t)plane * HW_ + p] = ps;
        xfreg[i] = pf;
        #pragma unroll
        for (int j = 0; j < 8; ++j) { fv[j] = fv2[j]; sv[j] = sv2[j]; }
    }
    red[g][lane] = ap;
    __syncthreads();
    if (t < 64) {
        float a = red[0][t] + red[1][t] + red[2][t] + red[3][t]
                + red[4][t] + red[5][t] + red[6][t] + red[7][t];
        attn_sm[t] = 1.f / (1.f + __expf(-a));
    }
    __syncthreads();
    float at = attn_sm[lane];
    #pragma unroll
    for (int i = 0; i < 4; ++i) {
        u16x8 pw;
        #pragma unroll
        for (int j = 0; j < 8; ++j)
            pw[j] = f2bf(bf2f(xfreg[i][j]) * at);
        XW[(size_t)((b * 8 + ks0 + 2 * i) * 4 + kq) * HW_ + p] = pw;
    }
}

// ---------------------------------------------------------------------------
// dist kernel: packed-uint fg list, integer d2, grid (8,32) x 512 thr.
// ---------------------------------------------------------------------------
__global__ __launch_bounds__(512) void dist_kernel(
    const float* __restrict__ mask, float* __restrict__ dist_raw,
    unsigned* __restrict__ dmax)
{
    __shared__ unsigned fg[4096];
    __shared__ int cnt;
    __shared__ float wmax[8];
    int b = blockIdx.x, tile = blockIdx.y;
    int t = threadIdx.x, lane = t & 63;
    if (t == 0) cnt = 0;
    __syncthreads();
    const float* mb = mask + (size_t)b * 65536;
    #pragma unroll
    for (int r = 0; r < 8; ++r) {
        int pp = r * 512 + t;
        int i = pp >> 6, j = pp & 63;
        bool pred = mb[i * 1024 + j * 4] > 0.5f;
        unsigned long long bal = __ballot(pred);
        int base = 0;
        if (lane == 0) base = atomicAdd(&cnt, __popcll(bal));
        base = __shfl(base, 0, 64);
        if (pred)
            fg[base + __popcll(bal & ((1ull << lane) - 1ull))] =
                (unsigned)((i << 8) | j);
    }
    __syncthreads();
    int nfg = cnt;
    int pix = tile * 128 + (t >> 2);
    int q = t & 3;
    int py = pix >> 6, px = pix & 63;
    int md = 0x7fffffff;
    #pragma unroll 4
    for (int it = q; it < nfg; it += 4) {
        unsigned e = fg[it];
        int dy = py - (int)(e >> 8);
        int dx = px - (int)(e & 255u);
        int d2 = dy * dy + dx * dx;
        md = min(md, d2);
    }
    md = min(md, __shfl_xor(md, 1, 64));
    md = min(md, __shfl_xor(md, 2, 64));
    float d = (nfg == 0) ? 1.0f : sqrtf((float)md);
    if (q == 0) dist_raw[b * HW_ + pix] = d;
    float mm = d;
    #pragma unroll
    for (int off = 1; off < 64; off <<= 1)
        mm = fmaxf(mm, __shfl_xor(mm, off, 64));
    if (lane == 0) wmax[t >> 6] = mm;
    __syncthreads();
    if (t == 0) {
        float M = wmax[0];
        #pragma unroll
        for (int i = 1; i < 8; ++i) M = fmaxf(M, wmax[i]);
        atomicMax(dmax + b, __float_as_uint(M));
    }
}

// ---------------------------------------------------------------------------
// MFMA GEMM, 2-phase double-buffered (guide §5.5 T3 minimum template):
// M=256, N=32768, K=768. 128o x 128n tile, 4 waves (64o x 64n), acc[4][4].
// Per iter: issue NEXT K-step's 4x global_load_lds into buf^1 FIRST, then
// ds_read+16 MFMA on buf, then ONE __syncthreads (drains residual vm+lgkm).
// Prefetch flies under compute -> residual latency only. LDS 32KB.
// XCD swizzle: v=(bx%8)*64+bx/8 puts the ot-pair sharing an X panel on the
// same XCD (bx, bx+8 -> v, v+1).
// Epilogue: + wd*dist, bf16 y store, BN partial stats.
// ---------------------------------------------------------------------------
__global__ __launch_bounds__(256) void gemm_kernel(
    const unsigned short* __restrict__ xf, const unsigned short* __restrict__ xs,
    const unsigned short* __restrict__ xw, const unsigned short* __restrict__ wprep,
    const float* __restrict__ w,
    const float* __restrict__ dist_raw, const unsigned* __restrict__ dmax,
    unsigned short* __restrict__ ybf,
    float* __restrict__ gsum, float* __restrict__ gsumsq)
{
    __shared__ u16x8 LA[2][512];   // [buf][kq(4)][o(128)] 16B chunks, 2x8KB
    __shared__ u16x8 LX[2][512];   // [buf][kq(4)][n(128)] 16B chunks, 2x8KB

    int bx0 = blockIdx.x;
    int v = (bx0 & 7) * 64 + (bx0 >> 3);        // bijective XCD swizzle (512%8==0)
    int ot = v & 1, nt = v >> 1;                // 2 o-tiles x 256 n-tiles
    int oBase = ot * 128, nBase = nt * 128;
    int b = nBase >> 12, pBase = nBase & 4095;
    int t = threadIdx.x, lane = t & 63, g = t >> 6;
    int wo = g >> 1, wn = g & 1;
    int l15 = lane & 15, kq = lane >> 4;
    int oW = oBase + wo * 64;

    const u16x8* WPc = (const u16x8*)wprep;
    const u16x8* XFc = (const u16x8*)xf;
    const u16x8* XSc = (const u16x8*)xs;
    const u16x8* XWc = (const u16x8*)xw;

    // staging decomposition: issue 0 covers slots [0,256) (kq 0..1),
    // issue 1 covers [256,512) (kq 2..3); thread t -> slot t (t+256).
    int kq0 = t >> 7;          // 0..1
    int kq1 = 2 + (t >> 7);    // 2..3
    int rl  = t & 127;

#define STAGE(buf, kn) { \
    int _k8 = (kn) & 7; \
    const u16x8* _Xs = ((kn) < 8) ? XFc : (((kn) < 16) ? XSc : XWc); \
    GLOAD16(WPc + ((kn) * 4 + kq0) * 256 + oBase + rl, &LA[buf][g * 64]); \
    GLOAD16(WPc + ((kn) * 4 + kq1) * 256 + oBase + rl, &LA[buf][256 + g * 64]); \
    GLOAD16(_Xs + (size_t)((b * 8 + _k8) * 4 + kq0) * HW_ + pBase + rl, &LX[buf][g * 64]); \
    GLOAD16(_Xs + (size_t)((b * 8 + _k8) * 4 + kq1) * HW_ + pBase + rl, &LX[buf][256 + g * 64]); }

    f32x4 acc[4][4];
    #pragma unroll
    for (int fo = 0; fo < 4; ++fo)
        #pragma unroll
        for (int fn = 0; fn < 4; ++fn)
            acc[fo][fn] = (f32x4){0.f, 0.f, 0.f, 0.f};

    // prologue: fill buf 0 with kn=0
    STAGE(0, 0);
    __syncthreads();

    #pragma unroll
    for (int kn = 0; kn < 24; ++kn) {
        int cur = kn & 1;
        if (kn < 23) STAGE(cur ^ 1, kn + 1);   // prefetch flies under compute
        const bf16x8* LAr = (const bf16x8*)&LA[cur][0];
        const bf16x8* LXr = (const bf16x8*)&LX[cur][0];
        bf16x8 af[4], xr[4];
        #pragma unroll
        for (int fo = 0; fo < 4; ++fo)
            af[fo] = LAr[kq * 128 + wo * 64 + fo * 16 + l15];
        #pragma unroll
        for (int fn = 0; fn < 4; ++fn)
            xr[fn] = LXr[kq * 128 + wn * 64 + fn * 16 + l15];
        #pragma unroll
        for (int fo = 0; fo < 4; ++fo)
            #pragma unroll
            for (int fn = 0; fn < 4; ++fn)
                acc[fo][fn] = __builtin_amdgcn_mfma_f32_16x16x32_bf16(
                    af[fo], xr[fn], acc[fo][fn], 0, 0, 0);
        __syncthreads();   // drains residual prefetch (vm) + my reads (lgkm)
    }
#undef STAGE

    // ---- epilogue ----
    float dinv = 1.0f / (__uint_as_float(dmax[b]) + 1e-6f);
    const float* dR = dist_raw + b * HW_ + pBase + wn * 64;
    float dn[4];
    #pragma unroll
    for (int fn = 0; fn < 4; ++fn)
        dn[fn] = dR[fn * 16 + l15] * dinv;

    float s_acc[4][4], ss_acc[4][4];
    #pragma unroll
    for (int fo = 0; fo < 4; ++fo) {
        #pragma unroll
        for (int r = 0; r < 4; ++r) {
            int o = oW + fo * 16 + kq * 4 + r;
            float wd = w[(size_t)o * KW_ + 768];
            float s = 0.f, ss = 0.f;
            #pragma unroll
            for (int fn = 0; fn < 4; ++fn) {
                float vv = acc[fo][fn][r] + wd * dn[fn];
                ybf[((size_t)(b * C_IN + o)) * HW_ + pBase + wn * 64 + fn * 16 + l15] = f2bf(vv);
                s += vv; ss += vv * vv;
            }
            s_acc[fo][r] = s; ss_acc[fo][r] = ss;
        }
    }
    #pragma unroll
    for (int m = 8; m; m >>= 1) {
        #pragma unroll
        for (int fo = 0; fo < 4; ++fo)
            #pragma unroll
            for (int r = 0; r < 4; ++r) {
                s_acc[fo][r]  += __shfl_xor(s_acc[fo][r],  m, 64);
                ss_acc[fo][r] += __shfl_xor(ss_acc[fo][r], m, 64);
            }
    }
    if (l15 == 0) {
        #pragma unroll
        for (int fo = 0; fo < 4; ++fo)
            #pragma unroll
            for (int r = 0; r < 4; ++r) {
                int o = oW + fo * 16 + kq * 4 + r;
                atomicAdd(&gsum[o],   s_acc[fo][r]);
                atomicAdd(&gsumsq[o], ss_acc[fo][r]);
            }
    }
}

// ---------------------------------------------------------------------------
// BN finalize + relu: read bf16 y, write fp32 out.
// ---------------------------------------------------------------------------
__global__ __launch_bounds__(256) void bn_kernel(
    const float* __restrict__ gsum, const float* __restrict__ gsumsq,
    const float* __restrict__ gamma, const float* __restrict__ beta,
    const unsigned short* __restrict__ ybf, float* __restrict__ out)
{
    int bo = blockIdx.x;
    int o = bo & 255;
    float mean = gsum[o] * (1.0f / NPIX_BN);
    float var  = gsumsq[o] * (1.0f / NPIX_BN) - mean * mean;
    float sc = gamma[o] * rsqrtf(var + 1e-5f);
    float sh = beta[o] - mean * sc;
    const u16x8* yp = (const u16x8*)(ybf + (size_t)bo * HW_);
    float4* op = (float4*)(out + (size_t)bo * HW_);
    int t = threadIdx.x;
    #pragma unroll
    for (int r = 0; r < 2; ++r) {
        u16x8 v = yp[r * 256 + t];
        float4 lo, hi;
        lo.x = fmaxf(bf2f(v[0]) * sc + sh, 0.f);
        lo.y = fmaxf(bf2f(v[1]) * sc + sh, 0.f);
        lo.z = fmaxf(bf2f(v[2]) * sc + sh, 0.f);
        lo.w = fmaxf(bf2f(v[3]) * sc + sh, 0.f);
        hi.x = fmaxf(bf2f(v[4]) * sc + sh, 0.f);
        hi.y = fmaxf(bf2f(v[5]) * sc + sh, 0.f);
        hi.z = fmaxf(bf2f(v[6]) * sc + sh, 0.f);
        hi.w = fmaxf(bf2f(v[7]) * sc + sh, 0.f);
        op[(r * 256 + t) * 2]     = lo;
        op[(r * 256 + t) * 2 + 1] = hi;
    }
}

// ---------------------------------------------------------------------------
// ws layout (float units):
//   [0,     32768)   dist_raw
//   [32768, 32776)   dmax (uint)
//   [32784, 33040)   gsum
//   [33040, 33296)   gsumsq
//   [33296, 131600)  wprep (196608 ushort)
//   [131600, ...)    staging:
//     P1 (ws >= ~68MB): XF | XS | XW | ybf (4 x 4194304 floats)
//     P2 (else):        XF,XS in d_out (consumed by gemm before bn rewrites
//                       d_out); XW | ybf in ws.
// ---------------------------------------------------------------------------
extern "C" void kernel_launch(void* const* d_in, const int* in_sizes, int n_in,
                              void* d_out, int out_size, void* d_ws, size_t ws_size,
                              hipStream_t stream)
{
    const float* f_s   = (const float*)d_in[0];
    const float* sfb   = (const float*)d_in[1];
    const float* mask  = (const float*)d_in[2];
    const float* w     = (const float*)d_in[3];
    const float* gamma = (const float*)d_in[4];
    const float* beta  = (const float*)d_in[5];
    float* out = (float*)d_out;
    float* ws  = (float*)d_ws;

    float*          dist_raw = ws;
    unsigned*       dmax     = (unsigned*)(ws + 32768);
    float*          gsum     = ws + 32784;
    float*          gsumsq   = ws + 33040;
    unsigned short* wprep    = (unsigned short*)(ws + 33296);

    const size_t P1_need = ((size_t)131600 + 4 * 4194304) * 4;  // ~67.6 MB
    unsigned short *xf, *xs, *xw, *ybf;
    if (ws_size >= P1_need) {
        xf  = (unsigned short*)(ws + 131600);
        xs  = (unsigned short*)(ws + 131600 + 1 * (size_t)4194304);
        xw  = (unsigned short*)(ws + 131600 + 2 * (size_t)4194304);
        ybf = (unsigned short*)(ws + 131600 + 3 * (size_t)4194304);
    } else {
        xf  = (unsigned short*)d_out;
        xs  = ((unsigned short*)d_out) + 8388608;
        xw  = (unsigned short*)(ws + 131600);
        ybf = (unsigned short*)(ws + 131600 + (size_t)4194304);
    }

    hipMemsetAsync(ws + 32768, 0, (33296 - 32768) * 4, stream);

    prep_w<<<768, 256, 0, stream>>>(w, wprep);
    conv_kernel<<<512, 512, 0, stream>>>(f_s, sfb, xf, xs, xw);
    dist_kernel<<<dim3(8, 32), 512, 0, stream>>>(mask, dist_raw, dmax);
    gemm_kernel<<<512, 256, 0, stream>>>(xf, xs, xw, wprep, w, dist_raw,
                                         dmax, ybf, gsum, gsumsq);
    bn_kernel<<<2048, 256, 0, stream>>>(gsum, gsumsq, gamma, beta, ybf, out);
}